// Round 3
// baseline (348.399 us; speedup 1.0000x reference)
//
#include <hip/hip_runtime.h>
#include <hip/hip_bf16.h>
#include <stdint.h>

typedef __hip_bfloat16 bf16;
typedef __attribute__((ext_vector_type(4))) short short4v;
typedef __attribute__((ext_vector_type(8))) short short8v;
typedef __attribute__((ext_vector_type(4))) float f32x4;

#define CAT8(lo,hi) __builtin_shufflevector(lo, hi, 0,1,2,3,4,5,6,7)
#define MFMA16(a,b,c) __builtin_amdgcn_mfma_f32_16x16x32_bf16(a,b,c,0,0,0)

__device__ __forceinline__ void gload16(const void* g, void* l) {
  __builtin_amdgcn_global_load_lds((const __attribute__((address_space(1))) unsigned int*)g,
                                   (__attribute__((address_space(3))) unsigned int*)l, 16, 0, 0);
}

// ---------------- convert x (f32 -> bf16), 4 elems/thread ----------------
__global__ __launch_bounds__(256) void k_cvt_x(const float* __restrict__ in, bf16* __restrict__ out) {
  int i = blockIdx.x*256 + threadIdx.x;
  float4 v = ((const float4*)in)[i];
  bf16* o = out + (size_t)i*4;
  o[0] = __float2bfloat16(v.x); o[1] = __float2bfloat16(v.y);
  o[2] = __float2bfloat16(v.z); o[3] = __float2bfloat16(v.w);
}

// ---------------- transpose-convert: W[K][N] f32 -> Wt[N][K] bf16 ----------------
__global__ __launch_bounds__(256) void k_transpose_cvt(const float* __restrict__ W, bf16* __restrict__ Wt,
                                                       int K, int N) {
  __shared__ float ts[64][65];
  int k0 = blockIdx.y*64, n0 = blockIdx.x*64;
  int t = threadIdx.x;
  #pragma unroll
  for (int ii = 0; ii < 16; ++ii) {
    int idx = ii*256 + t; int r = idx>>6, c = idx&63;
    ts[r][c] = W[(size_t)(k0+r)*N + n0 + c];
  }
  __syncthreads();
  #pragma unroll
  for (int ii = 0; ii < 16; ++ii) {
    int idx = ii*256 + t; int r = idx>>6, c = idx&63;   // r: n-row, c: k-col
    Wt[(size_t)(n0+r)*K + k0 + c] = __float2bfloat16(ts[c][r]);
  }
}

// ---------------- split-K GEMM: C[M][N] += A[M][K-slice] * Bt[N][K-slice]^T ----------------
// tile 128x128, BK=32, 256 threads (4 waves 2x2), blockIdx.z = K-split index.
// Output: f32 atomicAdd into zero-initialized C (device-scope, deterministic to ~1ulp).
__global__ __launch_bounds__(256) void k_gemm_bt_sk(const bf16* __restrict__ A, const bf16* __restrict__ Bt,
                                                    float* __restrict__ C, int M, int N, int K,
                                                    int KC, int ldc) {
  __shared__ bf16 Asm[128*32];
  __shared__ bf16 Bsm[128*32];
  const int t = threadIdx.x;
  const int lane = t & 63, w = t >> 6;
  const int wr = w >> 1, wc = w & 1;
  const int m0 = blockIdx.y*128, n0 = blockIdx.x*128;
  const int kbeg = blockIdx.z * KC, kend = kbeg + KC;
  const int kb = (lane>>4)*4;
  const int l15 = lane & 15;

  f32x4 acc[4][4];
  #pragma unroll
  for (int i = 0; i < 4; ++i)
    #pragma unroll
    for (int j = 0; j < 4; ++j) acc[i][j] = 0.f;

  const char* Ab = (const char*)A;
  const char* Bb = (const char*)Bt;
  const int off = t*16;          // byte offset into tile (linear)
  const int srow = off >> 6;     // 64 B per row (32 bf16)
  const int scolb = off & 63;

  for (int k0 = kbeg; k0 < kend; k0 += 32) {
    gload16(Ab + ((size_t)(m0+srow)*K + k0)*2 + scolb,      (char*)Asm + off);
    gload16(Ab + ((size_t)(m0+srow+64)*K + k0)*2 + scolb,   (char*)Asm + off + 4096);
    gload16(Bb + ((size_t)(n0+srow)*K + k0)*2 + scolb,      (char*)Bsm + off);
    gload16(Bb + ((size_t)(n0+srow+64)*K + k0)*2 + scolb,   (char*)Bsm + off + 4096);
    __syncthreads();

    short4v alo[4], ahi[4], blo[4], bhi[4];
    #pragma unroll
    for (int i = 0; i < 4; ++i) {
      const bf16* ap = Asm + (size_t)(wr*64 + i*16 + l15)*32;
      alo[i] = *(const short4v*)(ap + kb);
      ahi[i] = *(const short4v*)(ap + 16 + kb);
      const bf16* bp = Bsm + (size_t)(wc*64 + i*16 + l15)*32;
      blo[i] = *(const short4v*)(bp + kb);
      bhi[i] = *(const short4v*)(bp + 16 + kb);
    }
    #pragma unroll
    for (int i = 0; i < 4; ++i) {
      short8v a = CAT8(alo[i], ahi[i]);
      #pragma unroll
      for (int j = 0; j < 4; ++j) {
        short8v b = CAT8(blo[j], bhi[j]);
        acc[i][j] = MFMA16(a, b, acc[i][j]);
      }
    }
    __syncthreads();
  }

  #pragma unroll
  for (int i = 0; i < 4; ++i) {
    int row0 = m0 + wr*64 + i*16 + (lane>>4)*4;
    #pragma unroll
    for (int j = 0; j < 4; ++j) {
      int col = n0 + wc*64 + j*16 + l15;
      #pragma unroll
      for (int r = 0; r < 4; ++r)
        atomicAdd(&C[(size_t)(row0+r)*ldc + col], acc[i][j][r]);
    }
  }
}

// ---------------- fused RMSNorm + RoPE; V transpose-convert (reads f32 QKV) ----------------
__global__ __launch_bounds__(256) void k_normrope(const float* __restrict__ qkv,
    const float* __restrict__ cosb, const float* __restrict__ sinb,
    const float* __restrict__ qg, const float* __restrict__ kg,
    bf16* __restrict__ Qb, bf16* __restrict__ Kb, bf16* __restrict__ Vt) {
  int wid = blockIdx.x*4 + (threadIdx.x>>6);
  int lane = threadIdx.x & 63;
  int s = wid / 48, r = wid - s*48;
  int col;
  if (r < 32) col = r*64;
  else if (r < 40) col = 2048 + (r-32)*64;
  else col = 2560 + (r-40)*64;
  float v = qkv[(size_t)s*3072 + col + lane];
  if (r < 40) {
    float ss = v*v;
    #pragma unroll
    for (int o = 32; o; o >>= 1) ss += __shfl_xor(ss, o);
    float rms = rsqrtf(ss*(1.0f/64.0f) + 1e-6f);
    float g = (r < 32 ? qg : kg)[lane];
    float tn = v*rms*g;
    float other = __shfl_xor(tn, 32);
    float rot = (lane < 32) ? -other : other;
    float outv = tn*cosb[s*64+lane] + rot*sinb[s*64+lane];
    if (r < 32) Qb[((size_t)r*2048 + s)*64 + lane] = __float2bfloat16(outv);
    else        Kb[((size_t)(r-32)*2048 + s)*64 + lane] = __float2bfloat16(outv);
  } else {
    Vt[(size_t)(r-40)*64*2048 + (size_t)lane*2048 + s] = __float2bfloat16(v);
  }
}

// ---------------- causal flash attention v2 ----------------
// 512 threads (8 waves), QBLK=128 (16 q-rows/wave), KVBLK=64, heavy blocks first
#define SCALE2 0.18033688011f   /* (1/sqrt(64)) * log2(e) */
__global__ __launch_bounds__(512) void k_attn(const bf16* __restrict__ Qb, const bf16* __restrict__ Kb,
                                              const bf16* __restrict__ Vt, bf16* __restrict__ attnb) {
  __shared__ bf16 Ksm[64][68];
  __shared__ bf16 Vsm[64][68];
  __shared__ bf16 Plds[8][16][68];
  const int t = threadIdx.x, lane = t & 63, w = t >> 6;
  const int bid = blockIdx.x;
  const int h = bid & 31;
  const int qi = 15 - (bid >> 5);
  const int qb0 = qi * 128;
  const int kvh = h >> 2;
  const int kb = (lane>>4)*4;
  const int l15 = lane & 15;

  const bf16* Qh = Qb + (size_t)h*2048*64;
  const bf16* Kh = Kb + (size_t)kvh*2048*64;
  const bf16* Vh = Vt + (size_t)kvh*64*2048;

  const int qrow = qb0 + w*16 + l15;
  short4v qlo[2], qhi[2];
  #pragma unroll
  for (int kk = 0; kk < 2; ++kk) {
    qlo[kk] = *(const short4v*)(Qh + (size_t)qrow*64 + kk*32 + kb);
    qhi[kk] = *(const short4v*)(Qh + (size_t)qrow*64 + kk*32 + 16 + kb);
  }

  float m[4], ls[4];
  f32x4 o[4];
  #pragma unroll
  for (int r = 0; r < 4; ++r) { m[r] = -3e38f; ls[r] = 0.f; }
  #pragma unroll
  for (int j = 0; j < 4; ++j) o[j] = 0.f;

  const int srow = t >> 3;
  const int sc8  = (t & 7) * 8;
  const int qrow0 = qb0 + w*16 + (lane>>4)*4;

  const int nt = 2*qi + 2;
  for (int tt = 0; tt < nt; ++tt) {
    *(int4*)(&Ksm[srow][sc8]) = *(const int4*)(Kh + ((size_t)(tt*64 + srow))*64 + sc8);
    *(int4*)(&Vsm[srow][sc8]) = *(const int4*)(Vh + (size_t)srow*2048 + tt*64 + sc8);
    __syncthreads();

    f32x4 sAcc[4];
    #pragma unroll
    for (int j = 0; j < 4; ++j) sAcc[j] = 0.f;
    __builtin_amdgcn_s_setprio(1);
    #pragma unroll
    for (int kk = 0; kk < 2; ++kk) {
      short8v aq = CAT8(qlo[kk], qhi[kk]);
      #pragma unroll
      for (int j = 0; j < 4; ++j) {
        const bf16* kp = &Ksm[j*16 + l15][kk*32 + kb];
        short8v b = CAT8(*(const short4v*)kp, *(const short4v*)(kp + 16));
        sAcc[j] = MFMA16(aq, b, sAcc[j]);
      }
    }
    __builtin_amdgcn_s_setprio(0);

    float sc[4][4];
    #pragma unroll
    for (int j = 0; j < 4; ++j)
      #pragma unroll
      for (int r = 0; r < 4; ++r) sc[j][r] = sAcc[j][r]*SCALE2;
    if (tt*64 + 63 > qb0 + w*16) {
      #pragma unroll
      for (int j = 0; j < 4; ++j) {
        int colj = tt*64 + j*16 + l15;
        #pragma unroll
        for (int r = 0; r < 4; ++r) if (colj > qrow0 + r) sc[j][r] = -3e38f;
      }
    }

    #pragma unroll
    for (int r = 0; r < 4; ++r) {
      float mx = fmaxf(fmaxf(sc[0][r], sc[1][r]), fmaxf(sc[2][r], sc[3][r]));
      #pragma unroll
      for (int o_ = 8; o_; o_ >>= 1) mx = fmaxf(mx, __shfl_xor(mx, o_));
      float mn = fmaxf(m[r], mx);
      float alpha = exp2f(m[r] - mn);
      m[r] = mn;
      ls[r] *= alpha;
      #pragma unroll
      for (int j = 0; j < 4; ++j) o[j][r] *= alpha;
    }
    float rowsum[4] = {0.f, 0.f, 0.f, 0.f};
    #pragma unroll
    for (int j = 0; j < 4; ++j) {
      #pragma unroll
      for (int r = 0; r < 4; ++r) {
        float p = exp2f(sc[j][r] - m[r]);
        rowsum[r] += p;
        Plds[w][(lane>>4)*4 + r][j*16 + l15] = __float2bfloat16(p);
      }
    }
    #pragma unroll
    for (int r = 0; r < 4; ++r) {
      float rs = rowsum[r];
      #pragma unroll
      for (int o_ = 8; o_; o_ >>= 1) rs += __shfl_xor(rs, o_);
      ls[r] += rs;
    }

    __builtin_amdgcn_s_setprio(1);
    #pragma unroll
    for (int kk = 0; kk < 2; ++kk) {
      const bf16* pp = &Plds[w][l15][kk*32 + kb];
      short8v pa = CAT8(*(const short4v*)pp, *(const short4v*)(pp + 16));
      #pragma unroll
      for (int j = 0; j < 4; ++j) {
        const bf16* vp = &Vsm[j*16 + l15][kk*32 + kb];
        short8v bv = CAT8(*(const short4v*)vp, *(const short4v*)(vp + 16));
        o[j] = MFMA16(pa, bv, o[j]);
      }
    }
    __builtin_amdgcn_s_setprio(0);
    __syncthreads();
  }

  #pragma unroll
  for (int r = 0; r < 4; ++r) {
    float inv = 1.0f / ls[r];
    int row = qb0 + w*16 + (lane>>4)*4 + r;
    #pragma unroll
    for (int j = 0; j < 4; ++j)
      attnb[(size_t)row*2048 + h*64 + j*16 + l15] = __float2bfloat16(o[j][r]*inv);
  }
}

extern "C" void kernel_launch(void* const* d_in, const int* in_sizes, int n_in,
                              void* d_out, int out_size, void* d_ws, size_t ws_size,
                              hipStream_t stream) {
  const float* x    = (const float*)d_in[0];
  const float* cosb = (const float*)d_in[2];
  const float* sinb = (const float*)d_in[3];
  const float* Wq   = (const float*)d_in[4];
  const float* Wk   = (const float*)d_in[5];
  const float* Wv   = (const float*)d_in[6];
  const float* Wo   = (const float*)d_in[7];
  const float* qg   = (const float*)d_in[8];
  const float* kg   = (const float*)d_in[9];
  float* out = (float*)d_out;

  char* ws = (char*)d_ws;
  // phase 1-2 layout
  bf16*  xb    = (bf16*)(ws);                    // 8 MB    [2048][2048]
  bf16*  WqT   = (bf16*)(ws + 8388608);          // 8 MB    [2048][2048]
  bf16*  WkT   = (bf16*)(ws + 16777216);         // 2 MB
  bf16*  WvT   = (bf16*)(ws + 18874368);         // 2 MB
  bf16*  WoT   = (bf16*)(ws + 20971520);         // 8 MB    (live until out-proj)
  float* QKVf  = (float*)(ws + 29360128);        // 25.2 MB [2048][3072] f32 (atomic target)
  // phase 3-4 layout (overlays dead xb/WqT/WkT/WvT)
  bf16*  Qb    = (bf16*)(ws);                    // 8 MB    [32][2048][64]
  bf16*  Kb    = (bf16*)(ws + 8388608);          // 2 MB    [8][2048][64]
  bf16*  Vt    = (bf16*)(ws + 10485760);         // 2 MB    [8][64][2048]
  bf16*  attnb = (bf16*)(ws + 29360128);         // 8 MB    (overlays dead QKVf)
  // total ws footprint: 54,525,952 B (same as R1/R2 proven size)

  // zero atomic targets
  hipMemsetAsync(QKVf, 0, 25165824, stream);
  hipMemsetAsync(out, 0, (size_t)out_size*4, stream);

  // 1. convert / transpose weights + x
  k_cvt_x<<<4096, 256, 0, stream>>>(x, xb);
  k_transpose_cvt<<<dim3(32, 32), 256, 0, stream>>>(Wq, WqT, 2048, 2048);
  k_transpose_cvt<<<dim3(8, 32),  256, 0, stream>>>(Wk, WkT, 2048, 512);
  k_transpose_cvt<<<dim3(8, 32),  256, 0, stream>>>(Wv, WvT, 2048, 512);
  k_transpose_cvt<<<dim3(32, 32), 256, 0, stream>>>(Wo, WoT, 2048, 2048);

  // 2. fused QKV projection, split-K x2 (768 blocks)
  k_gemm_bt_sk<<<dim3(24, 16, 2), 256, 0, stream>>>(xb, WqT, QKVf, 2048, 3072, 2048, 1024, 3072);

  // 3. RMSNorm + RoPE (+ V transpose) — absorbs the f32 read
  k_normrope<<<24576, 256, 0, stream>>>(QKVf, cosb, sinb, qg, kg, Qb, Kb, Vt);

  // 4. causal flash attention
  k_attn<<<512, 512, 0, stream>>>(Qb, Kb, Vt, attnb);

  // 5. output projection, split-K x2 (512 blocks), atomicAdd into d_out
  k_gemm_bt_sk<<<dim3(16, 16, 2), 256, 0, stream>>>(attnb, WoT, out, 2048, 2048, 2048, 1024, 2048);
}

// Round 4
// 265.654 us; speedup vs baseline: 1.3115x; 1.3115x over previous
//
#include <hip/hip_runtime.h>
#include <hip/hip_bf16.h>
#include <stdint.h>

typedef __hip_bfloat16 bf16;
typedef __attribute__((ext_vector_type(4))) short short4v;
typedef __attribute__((ext_vector_type(8))) short short8v;
typedef __attribute__((ext_vector_type(4))) float f32x4;

#define CAT8(lo,hi) __builtin_shufflevector(lo, hi, 0,1,2,3,4,5,6,7)
#define MFMA16(a,b,c) __builtin_amdgcn_mfma_f32_16x16x32_bf16(a,b,c,0,0,0)

__device__ __forceinline__ void gload16(const void* g, void* l) {
  __builtin_amdgcn_global_load_lds((const __attribute__((address_space(1))) unsigned int*)g,
                                   (__attribute__((address_space(3))) unsigned int*)l, 16, 0, 0);
}

// ---------------- convert x (f32 -> bf16), 4 elems/thread ----------------
__global__ __launch_bounds__(256) void k_cvt_x(const float* __restrict__ in, bf16* __restrict__ out) {
  int i = blockIdx.x*256 + threadIdx.x;
  float4 v = ((const float4*)in)[i];
  bf16* o = out + (size_t)i*4;
  o[0] = __float2bfloat16(v.x); o[1] = __float2bfloat16(v.y);
  o[2] = __float2bfloat16(v.z); o[3] = __float2bfloat16(v.w);
}

// ---------------- transpose-convert: W[K][N] f32 -> Wt[N][K] bf16 ----------------
__global__ __launch_bounds__(256) void k_transpose_cvt(const float* __restrict__ W, bf16* __restrict__ Wt,
                                                       int K, int N) {
  __shared__ float ts[64][65];
  int k0 = blockIdx.y*64, n0 = blockIdx.x*64;
  int t = threadIdx.x;
  #pragma unroll
  for (int ii = 0; ii < 16; ++ii) {
    int idx = ii*256 + t; int r = idx>>6, c = idx&63;
    ts[r][c] = W[(size_t)(k0+r)*N + n0 + c];
  }
  __syncthreads();
  #pragma unroll
  for (int ii = 0; ii < 16; ++ii) {
    int idx = ii*256 + t; int r = idx>>6, c = idx&63;   // r: n-row, c: k-col
    Wt[(size_t)(n0+r)*K + k0 + c] = __float2bfloat16(ts[c][r]);
  }
}

// ---------------- split-K GEMM with LDS XOR-swizzle (T2, rule #21) ----------------
// tile 128x128, BK=32, 256 threads (4 waves 2x2), blockIdx.z = K-split index.
// LDS rows are 64 B (4 x 16-B chunks). Swizzle: chunk' = chunk ^ ((row>>1)&3).
// global_load_lds writes LINEARLY; the swizzle is realized by pre-swizzling the
// GLOBAL source column, and applying the same XOR on the ds_read side.
__global__ __launch_bounds__(256) void k_gemm_bt_sk(const bf16* __restrict__ A, const bf16* __restrict__ Bt,
                                                    float* __restrict__ C, int M, int N, int K,
                                                    int KC, int ldc) {
  __shared__ bf16 Asm[128*32];
  __shared__ bf16 Bsm[128*32];
  const int t = threadIdx.x;
  const int lane = t & 63, w = t >> 6;
  const int wr = w >> 1, wc = w & 1;
  const int m0 = blockIdx.y*128, n0 = blockIdx.x*128;
  const int kbeg = blockIdx.z * KC, kend = kbeg + KC;
  const int l15 = lane & 15;
  const int g8 = (lane >> 4) << 3;          // byte offset of lo-fragment within row

  f32x4 acc[4][4];
  #pragma unroll
  for (int i = 0; i < 4; ++i)
    #pragma unroll
    for (int j = 0; j < 4; ++j) acc[i][j] = 0.f;

  const char* Ab = (const char*)A;
  const char* Bb = (const char*)Bt;
  const int off  = t*16;                    // linear LDS byte offset this thread fills
  const int srow = off >> 6;                // tile row (64 B per row = 32 bf16)
  // inverse-swizzled global source column (16-B chunk permutation, involution)
  const int scolb = (((off >> 4) & 3) ^ ((srow >> 1) & 3)) << 4;
  // note: row srow+64 has the same ((row>>1)&3) as srow (64>>1=32, 32&3=0)

  for (int k0 = kbeg; k0 < kend; k0 += 32) {
    gload16(Ab + ((size_t)(m0+srow)*K + k0)*2 + scolb,      (char*)Asm + off);
    gload16(Ab + ((size_t)(m0+srow+64)*K + k0)*2 + scolb,   (char*)Asm + off + 4096);
    gload16(Bb + ((size_t)(n0+srow)*K + k0)*2 + scolb,      (char*)Bsm + off);
    gload16(Bb + ((size_t)(n0+srow+64)*K + k0)*2 + scolb,   (char*)Bsm + off + 4096);
    __syncthreads();

    short4v alo[4], ahi[4], blo[4], bhi[4];
    #pragma unroll
    for (int i = 0; i < 4; ++i) {
      const int arow = wr*64 + i*16 + l15;
      const int asw  = ((arow >> 1) & 3) << 4;
      const char* ap = (const char*)Asm + arow*64;
      alo[i] = *(const short4v*)(ap + (g8 ^ asw));
      ahi[i] = *(const short4v*)(ap + ((32 + g8) ^ asw));
      const int brow = wc*64 + i*16 + l15;
      const int bsw  = ((brow >> 1) & 3) << 4;
      const char* bp = (const char*)Bsm + brow*64;
      blo[i] = *(const short4v*)(bp + (g8 ^ bsw));
      bhi[i] = *(const short4v*)(bp + ((32 + g8) ^ bsw));
    }
    #pragma unroll
    for (int i = 0; i < 4; ++i) {
      short8v a = CAT8(alo[i], ahi[i]);
      #pragma unroll
      for (int j = 0; j < 4; ++j) {
        short8v b = CAT8(blo[j], bhi[j]);
        acc[i][j] = MFMA16(a, b, acc[i][j]);
      }
    }
    __syncthreads();
  }

  #pragma unroll
  for (int i = 0; i < 4; ++i) {
    int row0 = m0 + wr*64 + i*16 + ((lane>>4)<<2);
    #pragma unroll
    for (int j = 0; j < 4; ++j) {
      int col = n0 + wc*64 + j*16 + l15;
      #pragma unroll
      for (int r = 0; r < 4; ++r)
        atomicAdd(&C[(size_t)(row0+r)*ldc + col], acc[i][j][r]);
    }
  }
}

// ---------------- fused RMSNorm + RoPE; V transpose-convert (reads f32 QKV) ----------------
__global__ __launch_bounds__(256) void k_normrope(const float* __restrict__ qkv,
    const float* __restrict__ cosb, const float* __restrict__ sinb,
    const float* __restrict__ qg, const float* __restrict__ kg,
    bf16* __restrict__ Qb, bf16* __restrict__ Kb, bf16* __restrict__ Vt) {
  int wid = blockIdx.x*4 + (threadIdx.x>>6);
  int lane = threadIdx.x & 63;
  int s = wid / 48, r = wid - s*48;
  int col;
  if (r < 32) col = r*64;
  else if (r < 40) col = 2048 + (r-32)*64;
  else col = 2560 + (r-40)*64;
  float v = qkv[(size_t)s*3072 + col + lane];
  if (r < 40) {
    float ss = v*v;
    #pragma unroll
    for (int o = 32; o; o >>= 1) ss += __shfl_xor(ss, o);
    float rms = rsqrtf(ss*(1.0f/64.0f) + 1e-6f);
    float g = (r < 32 ? qg : kg)[lane];
    float tn = v*rms*g;
    float other = __shfl_xor(tn, 32);
    float rot = (lane < 32) ? -other : other;
    float outv = tn*cosb[s*64+lane] + rot*sinb[s*64+lane];
    if (r < 32) Qb[((size_t)r*2048 + s)*64 + lane] = __float2bfloat16(outv);
    else        Kb[((size_t)(r-32)*2048 + s)*64 + lane] = __float2bfloat16(outv);
  } else {
    Vt[(size_t)(r-40)*64*2048 + (size_t)lane*2048 + s] = __float2bfloat16(v);
  }
}

// ---------------- causal flash attention v2 ----------------
#define SCALE2 0.18033688011f   /* (1/sqrt(64)) * log2(e) */
__global__ __launch_bounds__(512) void k_attn(const bf16* __restrict__ Qb, const bf16* __restrict__ Kb,
                                              const bf16* __restrict__ Vt, bf16* __restrict__ attnb) {
  __shared__ bf16 Ksm[64][68];
  __shared__ bf16 Vsm[64][68];
  __shared__ bf16 Plds[8][16][68];
  const int t = threadIdx.x, lane = t & 63, w = t >> 6;
  const int bid = blockIdx.x;
  const int h = bid & 31;
  const int qi = 15 - (bid >> 5);
  const int qb0 = qi * 128;
  const int kvh = h >> 2;
  const int kb = (lane>>4)*4;
  const int l15 = lane & 15;

  const bf16* Qh = Qb + (size_t)h*2048*64;
  const bf16* Kh = Kb + (size_t)kvh*2048*64;
  const bf16* Vh = Vt + (size_t)kvh*64*2048;

  const int qrow = qb0 + w*16 + l15;
  short4v qlo[2], qhi[2];
  #pragma unroll
  for (int kk = 0; kk < 2; ++kk) {
    qlo[kk] = *(const short4v*)(Qh + (size_t)qrow*64 + kk*32 + kb);
    qhi[kk] = *(const short4v*)(Qh + (size_t)qrow*64 + kk*32 + 16 + kb);
  }

  float m[4], ls[4];
  f32x4 o[4];
  #pragma unroll
  for (int r = 0; r < 4; ++r) { m[r] = -3e38f; ls[r] = 0.f; }
  #pragma unroll
  for (int j = 0; j < 4; ++j) o[j] = 0.f;

  const int srow = t >> 3;
  const int sc8  = (t & 7) * 8;
  const int qrow0 = qb0 + w*16 + (lane>>4)*4;

  const int nt = 2*qi + 2;
  for (int tt = 0; tt < nt; ++tt) {
    *(int4*)(&Ksm[srow][sc8]) = *(const int4*)(Kh + ((size_t)(tt*64 + srow))*64 + sc8);
    *(int4*)(&Vsm[srow][sc8]) = *(const int4*)(Vh + (size_t)srow*2048 + tt*64 + sc8);
    __syncthreads();

    f32x4 sAcc[4];
    #pragma unroll
    for (int j = 0; j < 4; ++j) sAcc[j] = 0.f;
    __builtin_amdgcn_s_setprio(1);
    #pragma unroll
    for (int kk = 0; kk < 2; ++kk) {
      short8v aq = CAT8(qlo[kk], qhi[kk]);
      #pragma unroll
      for (int j = 0; j < 4; ++j) {
        const bf16* kp = &Ksm[j*16 + l15][kk*32 + kb];
        short8v b = CAT8(*(const short4v*)kp, *(const short4v*)(kp + 16));
        sAcc[j] = MFMA16(aq, b, sAcc[j]);
      }
    }
    __builtin_amdgcn_s_setprio(0);

    float sc[4][4];
    #pragma unroll
    for (int j = 0; j < 4; ++j)
      #pragma unroll
      for (int r = 0; r < 4; ++r) sc[j][r] = sAcc[j][r]*SCALE2;
    if (tt*64 + 63 > qb0 + w*16) {
      #pragma unroll
      for (int j = 0; j < 4; ++j) {
        int colj = tt*64 + j*16 + l15;
        #pragma unroll
        for (int r = 0; r < 4; ++r) if (colj > qrow0 + r) sc[j][r] = -3e38f;
      }
    }

    #pragma unroll
    for (int r = 0; r < 4; ++r) {
      float mx = fmaxf(fmaxf(sc[0][r], sc[1][r]), fmaxf(sc[2][r], sc[3][r]));
      #pragma unroll
      for (int o_ = 8; o_; o_ >>= 1) mx = fmaxf(mx, __shfl_xor(mx, o_));
      float mn = fmaxf(m[r], mx);
      float alpha = exp2f(m[r] - mn);
      m[r] = mn;
      ls[r] *= alpha;
      #pragma unroll
      for (int j = 0; j < 4; ++j) o[j][r] *= alpha;
    }
    float rowsum[4] = {0.f, 0.f, 0.f, 0.f};
    #pragma unroll
    for (int j = 0; j < 4; ++j) {
      #pragma unroll
      for (int r = 0; r < 4; ++r) {
        float p = exp2f(sc[j][r] - m[r]);
        rowsum[r] += p;
        Plds[w][(lane>>4)*4 + r][j*16 + l15] = __float2bfloat16(p);
      }
    }
    #pragma unroll
    for (int r = 0; r < 4; ++r) {
      float rs = rowsum[r];
      #pragma unroll
      for (int o_ = 8; o_; o_ >>= 1) rs += __shfl_xor(rs, o_);
      ls[r] += rs;
    }

    __builtin_amdgcn_s_setprio(1);
    #pragma unroll
    for (int kk = 0; kk < 2; ++kk) {
      const bf16* pp = &Plds[w][l15][kk*32 + kb];
      short8v pa = CAT8(*(const short4v*)pp, *(const short4v*)(pp + 16));
      #pragma unroll
      for (int j = 0; j < 4; ++j) {
        const bf16* vp = &Vsm[j*16 + l15][kk*32 + kb];
        short8v bv = CAT8(*(const short4v*)vp, *(const short4v*)(vp + 16));
        o[j] = MFMA16(pa, bv, o[j]);
      }
    }
    __builtin_amdgcn_s_setprio(0);
    __syncthreads();
  }

  #pragma unroll
  for (int r = 0; r < 4; ++r) {
    float inv = 1.0f / ls[r];
    int row = qb0 + w*16 + (lane>>4)*4 + r;
    #pragma unroll
    for (int j = 0; j < 4; ++j)
      attnb[(size_t)row*2048 + h*64 + j*16 + l15] = __float2bfloat16(o[j][r]*inv);
  }
}

extern "C" void kernel_launch(void* const* d_in, const int* in_sizes, int n_in,
                              void* d_out, int out_size, void* d_ws, size_t ws_size,
                              hipStream_t stream) {
  const float* x    = (const float*)d_in[0];
  const float* cosb = (const float*)d_in[2];
  const float* sinb = (const float*)d_in[3];
  const float* Wq   = (const float*)d_in[4];
  const float* Wk   = (const float*)d_in[5];
  const float* Wv   = (const float*)d_in[6];
  const float* Wo   = (const float*)d_in[7];
  const float* qg   = (const float*)d_in[8];
  const float* kg   = (const float*)d_in[9];
  float* out = (float*)d_out;

  char* ws = (char*)d_ws;
  // phase 1-2 layout
  bf16*  xb    = (bf16*)(ws);                    // 8 MB    [2048][2048]
  bf16*  WqT   = (bf16*)(ws + 8388608);          // 8 MB    [2048][2048]
  bf16*  WkT   = (bf16*)(ws + 16777216);         // 2 MB
  bf16*  WvT   = (bf16*)(ws + 18874368);         // 2 MB
  bf16*  WoT   = (bf16*)(ws + 20971520);         // 8 MB    (live until out-proj)
  float* QKVf  = (float*)(ws + 29360128);        // 25.2 MB [2048][3072] f32 (atomic target)
  // phase 3-4 layout (overlays dead xb/WqT/WkT/WvT)
  bf16*  Qb    = (bf16*)(ws);                    // 8 MB    [32][2048][64]
  bf16*  Kb    = (bf16*)(ws + 8388608);          // 2 MB    [8][2048][64]
  bf16*  Vt    = (bf16*)(ws + 10485760);         // 2 MB    [8][64][2048]
  bf16*  attnb = (bf16*)(ws + 29360128);         // 8 MB    (overlays dead QKVf)

  hipMemsetAsync(QKVf, 0, 25165824, stream);
  hipMemsetAsync(out, 0, (size_t)out_size*4, stream);

  k_cvt_x<<<4096, 256, 0, stream>>>(x, xb);
  k_transpose_cvt<<<dim3(32, 32), 256, 0, stream>>>(Wq, WqT, 2048, 2048);
  k_transpose_cvt<<<dim3(8, 32),  256, 0, stream>>>(Wk, WkT, 2048, 512);
  k_transpose_cvt<<<dim3(8, 32),  256, 0, stream>>>(Wv, WvT, 2048, 512);
  k_transpose_cvt<<<dim3(32, 32), 256, 0, stream>>>(Wo, WoT, 2048, 2048);

  k_gemm_bt_sk<<<dim3(24, 16, 2), 256, 0, stream>>>(xb, WqT, QKVf, 2048, 3072, 2048, 1024, 3072);
  k_normrope<<<24576, 256, 0, stream>>>(QKVf, cosb, sinb, qg, kg, Qb, Kb, Vt);
  k_attn<<<512, 512, 0, stream>>>(Qb, Kb, Vt, attnb);
  k_gemm_bt_sk<<<dim3(16, 16, 2), 256, 0, stream>>>(attnb, WoT, out, 2048, 2048, 2048, 1024, 2048);
}

// Round 5
// 240.306 us; speedup vs baseline: 1.4498x; 1.1055x over previous
//
#include <hip/hip_runtime.h>
#include <hip/hip_bf16.h>
#include <stdint.h>

typedef __hip_bfloat16 bf16;
typedef __attribute__((ext_vector_type(4))) short short4v;
typedef __attribute__((ext_vector_type(8))) short short8v;
typedef __attribute__((ext_vector_type(4))) float f32x4;

#define CAT8(lo,hi) __builtin_shufflevector(lo, hi, 0,1,2,3,4,5,6,7)
#define MFMA16(a,b,c) __builtin_amdgcn_mfma_f32_16x16x32_bf16(a,b,c,0,0,0)

__device__ __forceinline__ void gload16(const void* g, void* l) {
  __builtin_amdgcn_global_load_lds((const __attribute__((address_space(1))) unsigned int*)g,
                                   (__attribute__((address_space(3))) unsigned int*)l, 16, 0, 0);
}

__device__ __forceinline__ short f2bs(float f) {
  return __builtin_bit_cast(short, __float2bfloat16(f));
}

// ---------------- convert x (f32 -> bf16), 4 elems/thread ----------------
__global__ __launch_bounds__(256) void k_cvt_x(const float* __restrict__ in, bf16* __restrict__ out) {
  int i = blockIdx.x*256 + threadIdx.x;
  float4 v = ((const float4*)in)[i];
  bf16* o = out + (size_t)i*4;
  o[0] = __float2bfloat16(v.x); o[1] = __float2bfloat16(v.y);
  o[2] = __float2bfloat16(v.z); o[3] = __float2bfloat16(v.w);
}

// ---------------- transpose-convert: W[K][N] f32 -> Wt[N][K] bf16 ----------------
__global__ __launch_bounds__(256) void k_transpose_cvt(const float* __restrict__ W, bf16* __restrict__ Wt,
                                                       int K, int N) {
  __shared__ float ts[64][65];
  int k0 = blockIdx.y*64, n0 = blockIdx.x*64;
  int t = threadIdx.x;
  #pragma unroll
  for (int ii = 0; ii < 16; ++ii) {
    int idx = ii*256 + t; int r = idx>>6, c = idx&63;
    ts[r][c] = W[(size_t)(k0+r)*N + n0 + c];
  }
  __syncthreads();
  #pragma unroll
  for (int ii = 0; ii < 16; ++ii) {
    int idx = ii*256 + t; int r = idx>>6, c = idx&63;   // r: n-row, c: k-col
    Wt[(size_t)(n0+r)*K + k0 + c] = __float2bfloat16(ts[c][r]);
  }
}

// ---------------- split-K GEMM with LDS XOR-swizzle (T2) ----------------
__global__ __launch_bounds__(256) void k_gemm_bt_sk(const bf16* __restrict__ A, const bf16* __restrict__ Bt,
                                                    float* __restrict__ C, int M, int N, int K,
                                                    int KC, int ldc) {
  __shared__ bf16 Asm[128*32];
  __shared__ bf16 Bsm[128*32];
  const int t = threadIdx.x;
  const int lane = t & 63, w = t >> 6;
  const int wr = w >> 1, wc = w & 1;
  const int m0 = blockIdx.y*128, n0 = blockIdx.x*128;
  const int kbeg = blockIdx.z * KC, kend = kbeg + KC;
  const int l15 = lane & 15;
  const int g8 = (lane >> 4) << 3;          // byte offset of lo-fragment within row

  f32x4 acc[4][4];
  #pragma unroll
  for (int i = 0; i < 4; ++i)
    #pragma unroll
    for (int j = 0; j < 4; ++j) acc[i][j] = 0.f;

  const char* Ab = (const char*)A;
  const char* Bb = (const char*)Bt;
  const int off  = t*16;                    // linear LDS byte offset this thread fills
  const int srow = off >> 6;                // tile row (64 B per row = 32 bf16)
  const int scolb = (((off >> 4) & 3) ^ ((srow >> 1) & 3)) << 4;

  for (int k0 = kbeg; k0 < kend; k0 += 32) {
    gload16(Ab + ((size_t)(m0+srow)*K + k0)*2 + scolb,      (char*)Asm + off);
    gload16(Ab + ((size_t)(m0+srow+64)*K + k0)*2 + scolb,   (char*)Asm + off + 4096);
    gload16(Bb + ((size_t)(n0+srow)*K + k0)*2 + scolb,      (char*)Bsm + off);
    gload16(Bb + ((size_t)(n0+srow+64)*K + k0)*2 + scolb,   (char*)Bsm + off + 4096);
    __syncthreads();

    short4v alo[4], ahi[4], blo[4], bhi[4];
    #pragma unroll
    for (int i = 0; i < 4; ++i) {
      const int arow = wr*64 + i*16 + l15;
      const int asw  = ((arow >> 1) & 3) << 4;
      const char* ap = (const char*)Asm + arow*64;
      alo[i] = *(const short4v*)(ap + (g8 ^ asw));
      ahi[i] = *(const short4v*)(ap + ((32 + g8) ^ asw));
      const int brow = wc*64 + i*16 + l15;
      const int bsw  = ((brow >> 1) & 3) << 4;
      const char* bp = (const char*)Bsm + brow*64;
      blo[i] = *(const short4v*)(bp + (g8 ^ bsw));
      bhi[i] = *(const short4v*)(bp + ((32 + g8) ^ bsw));
    }
    #pragma unroll
    for (int i = 0; i < 4; ++i) {
      short8v a = CAT8(alo[i], ahi[i]);
      #pragma unroll
      for (int j = 0; j < 4; ++j) {
        short8v b = CAT8(blo[j], bhi[j]);
        acc[i][j] = MFMA16(a, b, acc[i][j]);
      }
    }
    __syncthreads();
  }

  #pragma unroll
  for (int i = 0; i < 4; ++i) {
    int row0 = m0 + wr*64 + i*16 + ((lane>>4)<<2);
    #pragma unroll
    for (int j = 0; j < 4; ++j) {
      int col = n0 + wc*64 + j*16 + l15;
      #pragma unroll
      for (int r = 0; r < 4; ++r)
        atomicAdd(&C[(size_t)(row0+r)*ldc + col], acc[i][j][r]);
    }
  }
}

// ---------------- fused RMSNorm + RoPE; V transpose-convert (reads f32 QKV) ----------------
__global__ __launch_bounds__(256) void k_normrope(const float* __restrict__ qkv,
    const float* __restrict__ cosb, const float* __restrict__ sinb,
    const float* __restrict__ qg, const float* __restrict__ kg,
    bf16* __restrict__ Qb, bf16* __restrict__ Kb, bf16* __restrict__ Vt) {
  int wid = blockIdx.x*4 + (threadIdx.x>>6);
  int lane = threadIdx.x & 63;
  int s = wid / 48, r = wid - s*48;
  int col;
  if (r < 32) col = r*64;
  else if (r < 40) col = 2048 + (r-32)*64;
  else col = 2560 + (r-40)*64;
  float v = qkv[(size_t)s*3072 + col + lane];
  if (r < 40) {
    float ss = v*v;
    #pragma unroll
    for (int o = 32; o; o >>= 1) ss += __shfl_xor(ss, o);
    float rms = rsqrtf(ss*(1.0f/64.0f) + 1e-6f);
    float g = (r < 32 ? qg : kg)[lane];
    float tn = v*rms*g;
    float other = __shfl_xor(tn, 32);
    float rot = (lane < 32) ? -other : other;
    float outv = tn*cosb[s*64+lane] + rot*sinb[s*64+lane];
    if (r < 32) Qb[((size_t)r*2048 + s)*64 + lane] = __float2bfloat16(outv);
    else        Kb[((size_t)(r-32)*2048 + s)*64 + lane] = __float2bfloat16(outv);
  } else {
    Vt[(size_t)(r-40)*64*2048 + (size_t)lane*2048 + s] = __float2bfloat16(v);
  }
}

// ---------------- causal flash attention v3: swapped-operand in-register softmax ----
// QK^T computed as mfma(K,Q) -> C[kv][q]: each lane owns ONE q-row (q = l15),
// 16 kv values in regs. C-layout of swapped QK^T == B-fragment layout of swapped
// PV (mfma(V^T,P) -> C[d][q]), so P feeds PV with ZERO data movement (no P LDS).
// Row reductions: 15 in-register ops + 2 shfl_xor (16,32) across the 4 replicated
// lane-groups. Softmax state m/ls are per-lane scalars.
#define SCALE2 0.18033688011f   /* (1/sqrt(64)) * log2(e) */
__global__ __launch_bounds__(512) void k_attn(const bf16* __restrict__ Qb, const bf16* __restrict__ Kb,
                                              const bf16* __restrict__ Vt, bf16* __restrict__ attnb) {
  __shared__ bf16 Ksm[64][68];
  __shared__ bf16 Vsm[64][68];
  const int t = threadIdx.x, lane = t & 63, w = t >> 6;
  const int bid = blockIdx.x;
  const int h = bid & 31;
  const int qi = 15 - (bid >> 5);          // heavy blocks first
  const int qb0 = qi * 128;
  const int kvh = h >> 2;
  const int kb = (lane>>4)*4;
  const int l15 = lane & 15;

  const bf16* Qh = Qb + (size_t)h*2048*64;
  const bf16* Kh = Kb + (size_t)kvh*2048*64;
  const bf16* Vh = Vt + (size_t)kvh*64*2048;

  const int qrow = qb0 + w*16 + l15;       // this lane's q-row (replicated x4 groups)
  short4v qlo[2], qhi[2];
  #pragma unroll
  for (int kk = 0; kk < 2; ++kk) {
    qlo[kk] = *(const short4v*)(Qh + (size_t)qrow*64 + kk*32 + kb);
    qhi[kk] = *(const short4v*)(Qh + (size_t)qrow*64 + kk*32 + 16 + kb);
  }

  float m_ = -3e38f, ls = 0.f;
  f32x4 o2[4];
  #pragma unroll
  for (int j = 0; j < 4; ++j) o2[j] = 0.f;

  const int srow = t >> 3;                 // staging: 512 thr, 1 int4 each for K and V
  const int sc8  = (t & 7) * 8;

  const int nt = 2*qi + 2;
  for (int tt = 0; tt < nt; ++tt) {
    *(int4*)(&Ksm[srow][sc8]) = *(const int4*)(Kh + ((size_t)(tt*64 + srow))*64 + sc8);
    *(int4*)(&Vsm[srow][sc8]) = *(const int4*)(Vh + (size_t)srow*2048 + tt*64 + sc8);
    __syncthreads();

    // S^T = K Q^T  (A = K-tile rows, B = Q rows) -> sAcc[j]: kv-block j, q = l15
    f32x4 sAcc[4];
    #pragma unroll
    for (int j = 0; j < 4; ++j) sAcc[j] = 0.f;
    __builtin_amdgcn_s_setprio(1);
    #pragma unroll
    for (int kk = 0; kk < 2; ++kk) {
      short8v bq = CAT8(qlo[kk], qhi[kk]);
      #pragma unroll
      for (int j = 0; j < 4; ++j) {
        const bf16* kp = &Ksm[j*16 + l15][kk*32 + kb];
        short8v ak = CAT8(*(const short4v*)kp, *(const short4v*)(kp + 16));
        sAcc[j] = MFMA16(ak, bq, sAcc[j]);
      }
    }
    __builtin_amdgcn_s_setprio(0);

    // scale (+ causal mask; skip when tile fully unmasked for this wave)
    float p[4][4];
    #pragma unroll
    for (int j = 0; j < 4; ++j)
      #pragma unroll
      for (int r = 0; r < 4; ++r) p[j][r] = sAcc[j][r]*SCALE2;
    if (tt*64 + 63 > qb0 + w*16) {
      #pragma unroll
      for (int j = 0; j < 4; ++j) {
        #pragma unroll
        for (int r = 0; r < 4; ++r)
          if (tt*64 + j*16 + kb + r > qrow) p[j][r] = -3e38f;
      }
    }

    // row max: 16 in-register values + cross-group combine
    float mx = p[0][0];
    #pragma unroll
    for (int j = 0; j < 4; ++j)
      #pragma unroll
      for (int r = 0; r < 4; ++r) mx = fmaxf(mx, p[j][r]);
    mx = fmaxf(mx, __shfl_xor(mx, 16));
    mx = fmaxf(mx, __shfl_xor(mx, 32));
    float mn = fmaxf(m_, mx);
    float alpha = exp2f(m_ - mn);
    m_ = mn;
    ls *= alpha;
    #pragma unroll
    for (int j = 0; j < 4; ++j) o2[j] *= alpha;

    float rs = 0.f;
    #pragma unroll
    for (int j = 0; j < 4; ++j)
      #pragma unroll
      for (int r = 0; r < 4; ++r) {
        float e = exp2f(p[j][r] - mn);
        p[j][r] = e;
        rs += e;
      }
    rs += __shfl_xor(rs, 16);
    rs += __shfl_xor(rs, 32);
    ls += rs;

    // pack P into PV B-fragments: chunk kk = m-blocks {2kk, 2kk+1}
    short8v pb[2];
    #pragma unroll
    for (int kk = 0; kk < 2; ++kk) {
      short8v v;
      v[0] = f2bs(p[2*kk][0]);   v[1] = f2bs(p[2*kk][1]);
      v[2] = f2bs(p[2*kk][2]);   v[3] = f2bs(p[2*kk][3]);
      v[4] = f2bs(p[2*kk+1][0]); v[5] = f2bs(p[2*kk+1][1]);
      v[6] = f2bs(p[2*kk+1][2]); v[7] = f2bs(p[2*kk+1][3]);
      pb[kk] = v;
    }

    // O^T += V^T P  (A = Vsm rows = d, B = P) -> o2[j]: d-block j, q = l15
    __builtin_amdgcn_s_setprio(1);
    #pragma unroll
    for (int kk = 0; kk < 2; ++kk) {
      #pragma unroll
      for (int j = 0; j < 4; ++j) {
        const bf16* vp = &Vsm[j*16 + l15][kk*32 + kb];
        short8v av = CAT8(*(const short4v*)vp, *(const short4v*)(vp + 16));
        o2[j] = MFMA16(av, pb[kk], o2[j]);
      }
    }
    __builtin_amdgcn_s_setprio(0);
    __syncthreads();
  }

  float inv = 1.0f / ls;
  #pragma unroll
  for (int j = 0; j < 4; ++j)
    #pragma unroll
    for (int r = 0; r < 4; ++r)
      attnb[(size_t)qrow*2048 + h*64 + j*16 + kb + r] = __float2bfloat16(o2[j][r]*inv);
}

extern "C" void kernel_launch(void* const* d_in, const int* in_sizes, int n_in,
                              void* d_out, int out_size, void* d_ws, size_t ws_size,
                              hipStream_t stream) {
  const float* x    = (const float*)d_in[0];
  const float* cosb = (const float*)d_in[2];
  const float* sinb = (const float*)d_in[3];
  const float* Wq   = (const float*)d_in[4];
  const float* Wk   = (const float*)d_in[5];
  const float* Wv   = (const float*)d_in[6];
  const float* Wo   = (const float*)d_in[7];
  const float* qg   = (const float*)d_in[8];
  const float* kg   = (const float*)d_in[9];
  float* out = (float*)d_out;

  char* ws = (char*)d_ws;
  // phase 1-2 layout
  bf16*  xb    = (bf16*)(ws);                    // 8 MB    [2048][2048]
  bf16*  WqT   = (bf16*)(ws + 8388608);          // 8 MB    [2048][2048]
  bf16*  WkT   = (bf16*)(ws + 16777216);         // 2 MB
  bf16*  WvT   = (bf16*)(ws + 18874368);         // 2 MB
  bf16*  WoT   = (bf16*)(ws + 20971520);         // 8 MB    (live until out-proj)
  float* QKVf  = (float*)(ws + 29360128);        // 25.2 MB [2048][3072] f32 (atomic target)
  // phase 3-4 layout (overlays dead xb/WqT/WkT/WvT)
  bf16*  Qb    = (bf16*)(ws);                    // 8 MB    [32][2048][64]
  bf16*  Kb    = (bf16*)(ws + 8388608);          // 2 MB    [8][2048][64]
  bf16*  Vt    = (bf16*)(ws + 10485760);         // 2 MB    [8][64][2048]
  bf16*  attnb = (bf16*)(ws + 29360128);         // 8 MB    (overlays dead QKVf)

  hipMemsetAsync(QKVf, 0, 25165824, stream);
  hipMemsetAsync(out, 0, (size_t)out_size*4, stream);

  k_cvt_x<<<4096, 256, 0, stream>>>(x, xb);
  k_transpose_cvt<<<dim3(32, 32), 256, 0, stream>>>(Wq, WqT, 2048, 2048);
  k_transpose_cvt<<<dim3(8, 32),  256, 0, stream>>>(Wk, WkT, 2048, 512);
  k_transpose_cvt<<<dim3(8, 32),  256, 0, stream>>>(Wv, WvT, 2048, 512);
  k_transpose_cvt<<<dim3(32, 32), 256, 0, stream>>>(Wo, WoT, 2048, 2048);

  k_gemm_bt_sk<<<dim3(24, 16, 2), 256, 0, stream>>>(xb, WqT, QKVf, 2048, 3072, 2048, 1024, 3072);
  k_normrope<<<24576, 256, 0, stream>>>(QKVf, cosb, sinb, qg, kg, Qb, Kb, Vt);
  k_attn<<<512, 512, 0, stream>>>(Qb, Kb, Vt, attnb);
  k_gemm_bt_sk<<<dim3(16, 16, 2), 256, 0, stream>>>(attnb, WoT, out, 2048, 2048, 2048, 1024, 2048);
}

// Round 6
// 234.989 us; speedup vs baseline: 1.4826x; 1.0226x over previous
//
#include <hip/hip_runtime.h>
#include <hip/hip_bf16.h>
#include <stdint.h>

typedef __hip_bfloat16 bf16;
typedef __attribute__((ext_vector_type(4))) short short4v;
typedef __attribute__((ext_vector_type(8))) short short8v;
typedef __attribute__((ext_vector_type(4))) float f32x4;

#define CAT8(lo,hi) __builtin_shufflevector(lo, hi, 0,1,2,3,4,5,6,7)
#define MFMA16(a,b,c) __builtin_amdgcn_mfma_f32_16x16x32_bf16(a,b,c,0,0,0)

__device__ __forceinline__ void gload16(const void* g, void* l) {
  __builtin_amdgcn_global_load_lds((const __attribute__((address_space(1))) unsigned int*)g,
                                   (__attribute__((address_space(3))) unsigned int*)l, 16, 0, 0);
}

__device__ __forceinline__ short f2bs(float f) {
  return __builtin_bit_cast(short, __float2bfloat16(f));
}

// ---------------- convert x (f32 -> bf16), 4 elems/thread ----------------
__global__ __launch_bounds__(256) void k_cvt_x(const float* __restrict__ in, bf16* __restrict__ out) {
  int i = blockIdx.x*256 + threadIdx.x;
  float4 v = ((const float4*)in)[i];
  bf16* o = out + (size_t)i*4;
  o[0] = __float2bfloat16(v.x); o[1] = __float2bfloat16(v.y);
  o[2] = __float2bfloat16(v.z); o[3] = __float2bfloat16(v.w);
}

// ---------------- transpose-convert: W[K][N] f32 -> Wt[N][K] bf16 ----------------
__global__ __launch_bounds__(256) void k_transpose_cvt(const float* __restrict__ W, bf16* __restrict__ Wt,
                                                       int K, int N) {
  __shared__ float ts[64][65];
  int k0 = blockIdx.y*64, n0 = blockIdx.x*64;
  int t = threadIdx.x;
  #pragma unroll
  for (int ii = 0; ii < 16; ++ii) {
    int idx = ii*256 + t; int r = idx>>6, c = idx&63;
    ts[r][c] = W[(size_t)(k0+r)*N + n0 + c];
  }
  __syncthreads();
  #pragma unroll
  for (int ii = 0; ii < 16; ++ii) {
    int idx = ii*256 + t; int r = idx>>6, c = idx&63;   // r: n-row, c: k-col
    Wt[(size_t)(n0+r)*K + k0 + c] = __float2bfloat16(ts[c][r]);
  }
}

// ---------------- split-K GEMM: T2 swizzle + T3-min double-buffer pipeline ----------------
// tile 128x128, BK=32, 256 threads (4 waves 2x2), blockIdx.z = K-split index.
// Pipeline: STAGE(t+1) issued BEFORE compute(t); s_waitcnt vmcnt(4) keeps the
// next tile's 4 global_load_lds in flight across the barrier (never drain to 0
// in the main loop). Raw s_barrier (NOT __syncthreads, which drains vmcnt).
__global__ __launch_bounds__(256) void k_gemm_bt_sk(const bf16* __restrict__ A, const bf16* __restrict__ Bt,
                                                    float* __restrict__ C, int M, int N, int K,
                                                    int KC, int ldc) {
  __shared__ bf16 Asm[2][128*32];
  __shared__ bf16 Bsm[2][128*32];
  const int t = threadIdx.x;
  const int lane = t & 63, w = t >> 6;
  const int wr = w >> 1, wc = w & 1;
  const int m0 = blockIdx.y*128, n0 = blockIdx.x*128;
  const int kbeg = blockIdx.z * KC, kend = kbeg + KC;
  const int l15 = lane & 15;
  const int g8 = (lane >> 4) << 3;          // byte offset of lo-fragment within row

  f32x4 acc[4][4];
  #pragma unroll
  for (int i = 0; i < 4; ++i)
    #pragma unroll
    for (int j = 0; j < 4; ++j) acc[i][j] = 0.f;

  const char* Ab = (const char*)A;
  const char* Bb = (const char*)Bt;
  const int off  = t*16;                    // linear LDS byte offset this thread fills
  const int srow = off >> 6;                // tile row (64 B per row = 32 bf16)
  const int scolb = (((off >> 4) & 3) ^ ((srow >> 1) & 3)) << 4;   // inverse bank-swizzle on source

  const size_t arow0 = (size_t)(m0+srow)*K, arow1 = (size_t)(m0+srow+64)*K;
  const size_t brow0 = (size_t)(n0+srow)*K, brow1 = (size_t)(n0+srow+64)*K;

#define STAGE(buf, kk)  do {                                          \
    gload16(Ab + (arow0 + (kk))*2 + scolb, (char*)Asm[buf] + off);    \
    gload16(Ab + (arow1 + (kk))*2 + scolb, (char*)Asm[buf] + off + 4096); \
    gload16(Bb + (brow0 + (kk))*2 + scolb, (char*)Bsm[buf] + off);    \
    gload16(Bb + (brow1 + (kk))*2 + scolb, (char*)Bsm[buf] + off + 4096); \
  } while (0)

  STAGE(0, kbeg);
  int cur = 0;

  for (int k0 = kbeg; k0 < kend; k0 += 32) {
    if (k0 + 32 < kend) {
      STAGE(cur ^ 1, k0 + 32);                       // prefetch next tile
      asm volatile("s_waitcnt vmcnt(4)" ::: "memory");  // wait ONLY current tile's loads
    } else {
      asm volatile("s_waitcnt vmcnt(0)" ::: "memory");
    }
    __builtin_amdgcn_s_barrier();                    // tile visible to all waves
    __builtin_amdgcn_sched_barrier(0);

    const bf16* Ac = Asm[cur];
    const bf16* Bc = Bsm[cur];
    short4v alo[4], ahi[4], blo[4], bhi[4];
    #pragma unroll
    for (int i = 0; i < 4; ++i) {
      const int arow = wr*64 + i*16 + l15;
      const int asw  = ((arow >> 1) & 3) << 4;
      const char* ap = (const char*)Ac + arow*64;
      alo[i] = *(const short4v*)(ap + (g8 ^ asw));
      ahi[i] = *(const short4v*)(ap + ((32 + g8) ^ asw));
      const int brow = wc*64 + i*16 + l15;
      const int bsw  = ((brow >> 1) & 3) << 4;
      const char* bp = (const char*)Bc + brow*64;
      blo[i] = *(const short4v*)(bp + (g8 ^ bsw));
      bhi[i] = *(const short4v*)(bp + ((32 + g8) ^ bsw));
    }
    #pragma unroll
    for (int i = 0; i < 4; ++i) {
      short8v a = CAT8(alo[i], ahi[i]);
      #pragma unroll
      for (int j = 0; j < 4; ++j) {
        short8v b = CAT8(blo[j], bhi[j]);
        acc[i][j] = MFMA16(a, b, acc[i][j]);
      }
    }
    __builtin_amdgcn_sched_barrier(0);
    __builtin_amdgcn_s_barrier();                    // all waves done reading cur
    cur ^= 1;
  }
#undef STAGE

  #pragma unroll
  for (int i = 0; i < 4; ++i) {
    int row0 = m0 + wr*64 + i*16 + ((lane>>4)<<2);
    #pragma unroll
    for (int j = 0; j < 4; ++j) {
      int col = n0 + wc*64 + j*16 + l15;
      #pragma unroll
      for (int r = 0; r < 4; ++r)
        atomicAdd(&C[(size_t)(row0+r)*ldc + col], acc[i][j][r]);
    }
  }
}

// ---------------- fused RMSNorm + RoPE; V transpose-convert (reads f32 QKV) ----------------
__global__ __launch_bounds__(256) void k_normrope(const float* __restrict__ qkv,
    const float* __restrict__ cosb, const float* __restrict__ sinb,
    const float* __restrict__ qg, const float* __restrict__ kg,
    bf16* __restrict__ Qb, bf16* __restrict__ Kb, bf16* __restrict__ Vt) {
  int wid = blockIdx.x*4 + (threadIdx.x>>6);
  int lane = threadIdx.x & 63;
  int s = wid / 48, r = wid - s*48;
  int col;
  if (r < 32) col = r*64;
  else if (r < 40) col = 2048 + (r-32)*64;
  else col = 2560 + (r-40)*64;
  float v = qkv[(size_t)s*3072 + col + lane];
  if (r < 40) {
    float ss = v*v;
    #pragma unroll
    for (int o = 32; o; o >>= 1) ss += __shfl_xor(ss, o);
    float rms = rsqrtf(ss*(1.0f/64.0f) + 1e-6f);
    float g = (r < 32 ? qg : kg)[lane];
    float tn = v*rms*g;
    float other = __shfl_xor(tn, 32);
    float rot = (lane < 32) ? -other : other;
    float outv = tn*cosb[s*64+lane] + rot*sinb[s*64+lane];
    if (r < 32) Qb[((size_t)r*2048 + s)*64 + lane] = __float2bfloat16(outv);
    else        Kb[((size_t)(r-32)*2048 + s)*64 + lane] = __float2bfloat16(outv);
  } else {
    Vt[(size_t)(r-40)*64*2048 + (size_t)lane*2048 + s] = __float2bfloat16(v);
  }
}

// ---------------- causal flash attention v3: swapped-operand in-register softmax ----
#define SCALE2 0.18033688011f   /* (1/sqrt(64)) * log2(e) */
__global__ __launch_bounds__(512) void k_attn(const bf16* __restrict__ Qb, const bf16* __restrict__ Kb,
                                              const bf16* __restrict__ Vt, bf16* __restrict__ attnb) {
  __shared__ bf16 Ksm[64][68];
  __shared__ bf16 Vsm[64][68];
  const int t = threadIdx.x, lane = t & 63, w = t >> 6;
  const int bid = blockIdx.x;
  const int h = bid & 31;
  const int qi = 15 - (bid >> 5);          // heavy blocks first
  const int qb0 = qi * 128;
  const int kvh = h >> 2;
  const int kb = (lane>>4)*4;
  const int l15 = lane & 15;

  const bf16* Qh = Qb + (size_t)h*2048*64;
  const bf16* Kh = Kb + (size_t)kvh*2048*64;
  const bf16* Vh = Vt + (size_t)kvh*64*2048;

  const int qrow = qb0 + w*16 + l15;       // this lane's q-row (replicated x4 groups)
  short4v qlo[2], qhi[2];
  #pragma unroll
  for (int kk = 0; kk < 2; ++kk) {
    qlo[kk] = *(const short4v*)(Qh + (size_t)qrow*64 + kk*32 + kb);
    qhi[kk] = *(const short4v*)(Qh + (size_t)qrow*64 + kk*32 + 16 + kb);
  }

  float m_ = -3e38f, ls = 0.f;
  f32x4 o2[4];
  #pragma unroll
  for (int j = 0; j < 4; ++j) o2[j] = 0.f;

  const int srow = t >> 3;                 // staging: 512 thr, 1 int4 each for K and V
  const int sc8  = (t & 7) * 8;

  const int nt = 2*qi + 2;
  for (int tt = 0; tt < nt; ++tt) {
    *(int4*)(&Ksm[srow][sc8]) = *(const int4*)(Kh + ((size_t)(tt*64 + srow))*64 + sc8);
    *(int4*)(&Vsm[srow][sc8]) = *(const int4*)(Vh + (size_t)srow*2048 + tt*64 + sc8);
    __syncthreads();

    // S^T = K Q^T -> sAcc[j]: kv-block j, q = l15
    f32x4 sAcc[4];
    #pragma unroll
    for (int j = 0; j < 4; ++j) sAcc[j] = 0.f;
    __builtin_amdgcn_s_setprio(1);
    #pragma unroll
    for (int kk = 0; kk < 2; ++kk) {
      short8v bq = CAT8(qlo[kk], qhi[kk]);
      #pragma unroll
      for (int j = 0; j < 4; ++j) {
        const bf16* kp = &Ksm[j*16 + l15][kk*32 + kb];
        short8v ak = CAT8(*(const short4v*)kp, *(const short4v*)(kp + 16));
        sAcc[j] = MFMA16(ak, bq, sAcc[j]);
      }
    }
    __builtin_amdgcn_s_setprio(0);

    float p[4][4];
    #pragma unroll
    for (int j = 0; j < 4; ++j)
      #pragma unroll
      for (int r = 0; r < 4; ++r) p[j][r] = sAcc[j][r]*SCALE2;
    if (tt*64 + 63 > qb0 + w*16) {
      #pragma unroll
      for (int j = 0; j < 4; ++j) {
        #pragma unroll
        for (int r = 0; r < 4; ++r)
          if (tt*64 + j*16 + kb + r > qrow) p[j][r] = -3e38f;
      }
    }

    float mx = p[0][0];
    #pragma unroll
    for (int j = 0; j < 4; ++j)
      #pragma unroll
      for (int r = 0; r < 4; ++r) mx = fmaxf(mx, p[j][r]);
    mx = fmaxf(mx, __shfl_xor(mx, 16));
    mx = fmaxf(mx, __shfl_xor(mx, 32));
    float mn = fmaxf(m_, mx);
    float alpha = exp2f(m_ - mn);
    m_ = mn;
    ls *= alpha;
    #pragma unroll
    for (int j = 0; j < 4; ++j) o2[j] *= alpha;

    float rs = 0.f;
    #pragma unroll
    for (int j = 0; j < 4; ++j)
      #pragma unroll
      for (int r = 0; r < 4; ++r) {
        float e = exp2f(p[j][r] - mn);
        p[j][r] = e;
        rs += e;
      }
    rs += __shfl_xor(rs, 16);
    rs += __shfl_xor(rs, 32);
    ls += rs;

    short8v pb[2];
    #pragma unroll
    for (int kk = 0; kk < 2; ++kk) {
      short8v v;
      v[0] = f2bs(p[2*kk][0]);   v[1] = f2bs(p[2*kk][1]);
      v[2] = f2bs(p[2*kk][2]);   v[3] = f2bs(p[2*kk][3]);
      v[4] = f2bs(p[2*kk+1][0]); v[5] = f2bs(p[2*kk+1][1]);
      v[6] = f2bs(p[2*kk+1][2]); v[7] = f2bs(p[2*kk+1][3]);
      pb[kk] = v;
    }

    // O^T += V^T P -> o2[j]: d-block j, q = l15
    __builtin_amdgcn_s_setprio(1);
    #pragma unroll
    for (int kk = 0; kk < 2; ++kk) {
      #pragma unroll
      for (int j = 0; j < 4; ++j) {
        const bf16* vp = &Vsm[j*16 + l15][kk*32 + kb];
        short8v av = CAT8(*(const short4v*)vp, *(const short4v*)(vp + 16));
        o2[j] = MFMA16(av, pb[kk], o2[j]);
      }
    }
    __builtin_amdgcn_s_setprio(0);
    __syncthreads();
  }

  float inv = 1.0f / ls;
  #pragma unroll
  for (int j = 0; j < 4; ++j)
    #pragma unroll
    for (int r = 0; r < 4; ++r)
      attnb[(size_t)qrow*2048 + h*64 + j*16 + kb + r] = __float2bfloat16(o2[j][r]*inv);
}

extern "C" void kernel_launch(void* const* d_in, const int* in_sizes, int n_in,
                              void* d_out, int out_size, void* d_ws, size_t ws_size,
                              hipStream_t stream) {
  const float* x    = (const float*)d_in[0];
  const float* cosb = (const float*)d_in[2];
  const float* sinb = (const float*)d_in[3];
  const float* Wq   = (const float*)d_in[4];
  const float* Wk   = (const float*)d_in[5];
  const float* Wv   = (const float*)d_in[6];
  const float* Wo   = (const float*)d_in[7];
  const float* qg   = (const float*)d_in[8];
  const float* kg   = (const float*)d_in[9];
  float* out = (float*)d_out;

  char* ws = (char*)d_ws;
  // phase 1-2 layout
  bf16*  xb    = (bf16*)(ws);                    // 8 MB    [2048][2048]
  bf16*  WqT   = (bf16*)(ws + 8388608);          // 8 MB    [2048][2048]
  bf16*  WkT   = (bf16*)(ws + 16777216);         // 2 MB
  bf16*  WvT   = (bf16*)(ws + 18874368);         // 2 MB
  bf16*  WoT   = (bf16*)(ws + 20971520);         // 8 MB    (live until out-proj)
  float* QKVf  = (float*)(ws + 29360128);        // 25.2 MB [2048][3072] f32 (atomic target)
  // phase 3-4 layout (overlays dead xb/WqT/WkT/WvT)
  bf16*  Qb    = (bf16*)(ws);                    // 8 MB    [32][2048][64]
  bf16*  Kb    = (bf16*)(ws + 8388608);          // 2 MB    [8][2048][64]
  bf16*  Vt    = (bf16*)(ws + 10485760);         // 2 MB    [8][64][2048]
  bf16*  attnb = (bf16*)(ws + 29360128);         // 8 MB    (overlays dead QKVf)

  hipMemsetAsync(QKVf, 0, 25165824, stream);
  hipMemsetAsync(out, 0, (size_t)out_size*4, stream);

  k_cvt_x<<<4096, 256, 0, stream>>>(x, xb);
  k_transpose_cvt<<<dim3(32, 32), 256, 0, stream>>>(Wq, WqT, 2048, 2048);
  k_transpose_cvt<<<dim3(8, 32),  256, 0, stream>>>(Wk, WkT, 2048, 512);
  k_transpose_cvt<<<dim3(8, 32),  256, 0, stream>>>(Wv, WvT, 2048, 512);
  k_transpose_cvt<<<dim3(32, 32), 256, 0, stream>>>(Wo, WoT, 2048, 2048);

  k_gemm_bt_sk<<<dim3(24, 16, 2), 256, 0, stream>>>(xb, WqT, QKVf, 2048, 3072, 2048, 1024, 3072);
  k_normrope<<<24576, 256, 0, stream>>>(QKVf, cosb, sinb, qg, kg, Qb, Kb, Vt);
  k_attn<<<512, 512, 0, stream>>>(Qb, Kb, Vt, attnb);
  k_gemm_bt_sk<<<dim3(16, 16, 2), 256, 0, stream>>>(attnb, WoT, out, 2048, 2048, 2048, 1024, 2048);
}